// Round 3
// baseline (169.772 us; speedup 1.0000x reference)
//
#include <hip/hip_runtime.h>
#include <math.h>

// Problem constants
#define B_ 16
#define C_ 256
#define H_ 64
#define W_ 64
#define G_ 8
#define CG_ 32
#define HID_ 64

typedef __attribute__((ext_vector_type(8))) short short8;
typedef __attribute__((ext_vector_type(4))) float floatx4;

__device__ inline unsigned short f2bf(float f) {
    union { float f; unsigned u; } v; v.f = f;
    unsigned r = v.u + 0x7fffu + ((v.u >> 16) & 1u);  // round-to-nearest-even
    return (unsigned short)(r >> 16);
}

// async global->LDS 16B copy (wave-uniform LDS base + lane*16 — all call sites
// keep lane-contiguous LDS destinations and wave-uniform branches)
__device__ __forceinline__ void gld16(const void* g, void* l) {
    __builtin_amdgcn_global_load_lds(
        (const __attribute__((address_space(1))) unsigned int*)g,
        (__attribute__((address_space(3))) unsigned int*)l, 16, 0, 0);
}

// ---- Kernel 1: transpose x -> bf16 xT[bg][h][q][w][8ci]  +  rowsum[bg][h][ci] ----
// block = (bg,h): 256 threads, wave q handles ci-octet q; lane w = column.
__global__ void xpose_pool(const float* __restrict__ x,
                           unsigned short* __restrict__ xT,
                           float* __restrict__ rowsum) {
    int bid = blockIdx.x;           // bg*64 + h
    int tid = threadIdx.x;
    int w = tid & 63, q = tid >> 6; // q = wave id (0..3)
    int h = bid & 63, bg = bid >> 6;

    const float* src = x + (((size_t)bg * 32 + q * 8) * 64 + h) * 64 + w;
    float v[8];
#pragma unroll
    for (int j = 0; j < 8; ++j) v[j] = __builtin_nontemporal_load(&src[(size_t)j * 4096]);

    short8 sv;
#pragma unroll
    for (int j = 0; j < 8; ++j) sv[j] = (short)f2bf(v[j]);
    *(short8*)(xT + ((size_t)(bid * 4 + q) * 64 + w) * 8) = sv;

    // per-ci row sums: reduce each v[j] over the 64 w-lanes
#pragma unroll
    for (int j = 0; j < 8; ++j) {
#pragma unroll
        for (int off = 32; off > 0; off >>= 1) v[j] += __shfl_down(v[j], off, 64);
    }
    if (w == 0) {
        float* rs = rowsum + (size_t)bid * 32 + q * 8;
#pragma unroll
        for (int j = 0; j < 8; ++j) rs[j] = v[j];
    }
}

// ---------------- Kernel 2: MLPs -> angles[B,G], mod[B,C] ----------------
// rowsum block slice for b: 16384 floats (64 KB) contiguous. Stage in two 32 KB
// halves via global_load_lds (coalesced), reduce over h from LDS (2 lanes/bank = free).
__global__ void mlp_kernel(const float* __restrict__ rowsum,
                           const float* __restrict__ ap_w1, const float* __restrict__ ap_b1,
                           const float* __restrict__ ap_w2, const float* __restrict__ ap_b2,
                           const float* __restrict__ mw1, const float* __restrict__ mb1,
                           const float* __restrict__ mw2, const float* __restrict__ mb2,
                           float* __restrict__ angles, float* __restrict__ modg) {
    int b = blockIdx.x, tid = threadIdx.x;
    __shared__ __align__(16) float sL[8192];   // 32 KB staging
    __shared__ __align__(16) float sp[C_];
    __shared__ __align__(16) float ha[HID_], hm[HID_];

    const float* rs = rowsum + (size_t)b * 16384;
    float s = 0.f;
#pragma unroll
    for (int p = 0; p < 2; ++p) {
        // stage 8192 floats = 2048 16B-chunks: chunk = tid + i*256
#pragma unroll
        for (int i = 0; i < 8; ++i) {
            int chunk = tid + i * 256;
            gld16(rs + (size_t)p * 8192 + chunk * 4, &sL[chunk * 4]);
        }
        __syncthreads();   // drains vmcnt before barrier
        // pass p holds g in [4p, 4p+4): threads 128p..128p+127 accumulate
        if ((tid >> 7) == p) {
            int gl = (tid >> 5) & 3, ci = tid & 31;
            const float* base = &sL[gl * 2048 + ci];
#pragma unroll
            for (int h = 0; h < 64; ++h) s += base[h * 32];
        }
        __syncthreads();
    }
    sp[tid] = s * (1.0f / 4096.0f);
    __syncthreads();

    if (tid < 64) {
        const float4* wr = (const float4*)(ap_w1 + tid * C_);
        const float4* p4 = (const float4*)sp;
        float s2 = ap_b1[tid];
#pragma unroll
        for (int i = 0; i < 64; ++i) {
            float4 wv = wr[i], pv = p4[i];
            s2 = fmaf(pv.x, wv.x, s2); s2 = fmaf(pv.y, wv.y, s2);
            s2 = fmaf(pv.z, wv.z, s2); s2 = fmaf(pv.w, wv.w, s2);
        }
        ha[tid] = fmaxf(s2, 0.f);
    } else if (tid < 128) {
        int t = tid - 64;
        const float4* wr = (const float4*)(mw1 + t * C_);
        const float4* p4 = (const float4*)sp;
        float s2 = mb1[t];
#pragma unroll
        for (int i = 0; i < 64; ++i) {
            float4 wv = wr[i], pv = p4[i];
            s2 = fmaf(pv.x, wv.x, s2); s2 = fmaf(pv.y, wv.y, s2);
            s2 = fmaf(pv.z, wv.z, s2); s2 = fmaf(pv.w, wv.w, s2);
        }
        hm[t] = fmaxf(s2, 0.f);
    }
    __syncthreads();

    if (tid < G_) {
        const float* wr = ap_w2 + tid * HID_;
        float s2 = ap_b2[tid];
        for (int i = 0; i < HID_; ++i) s2 = fmaf(ha[i], wr[i], s2);
        angles[b * G_ + tid] = tanhf(s2) * 0.78539816339744830962f;  // pi/4
    }
    {
        const float* wr = mw2 + tid * HID_;
        float s2 = mb2[tid];
        for (int i = 0; i < HID_; ++i) s2 = fmaf(hm[i], wr[i], s2);
        modg[b * C_ + tid] = 1.0f / (1.0f + expf(-s2));
    }
}

// ---------------- Kernel 3: bilinear rotation -> rotw bf16 [bg][k9][co][ci] ----------------
__global__ void rot_kernel(const float* __restrict__ base, const float* __restrict__ angles,
                           unsigned short* __restrict__ rotw) {
    int e = blockIdx.x * 256 + threadIdx.x;  // total B*G*9*32*32 = 1179648
    int ci = e & 31;
    int co = (e >> 5) & 31;
    int t = e >> 10;       // bg*9 + k
    int k = t % 9;
    int bg = t / 9;
    int b = bg >> 3, g = bg & 7;

    float ang = angles[b * G_ + g];
    float cc = __cosf(ang), ss = __sinf(ang);
    int i = k / 3, j = k % 3;
    float fx = (float)(j - 1), fy = (float)(i - 1);
    float xr = fx * cc + fy * ss + 1.0f;
    float yr = -fx * ss + fy * cc + 1.0f;
    float x0f = fminf(fmaxf(floorf(xr), 0.f), 1.f);
    float y0f = fminf(fmaxf(floorf(yr), 0.f), 1.f);
    float w00 = (x0f + 1.f - xr) * (y0f + 1.f - yr);
    float w01 = (x0f + 1.f - xr) * (yr - y0f);
    float w10 = (xr - x0f) * (y0f + 1.f - yr);
    float w11 = (xr - x0f) * (yr - y0f);
    int x0 = (int)x0f, y0 = (int)y0f;

    const float* bk = base + (((size_t)(g * CG_ + co) * CG_ + ci) * 9);
    float v = w00 * bk[y0 * 3 + x0] + w01 * bk[(y0 + 1) * 3 + x0] +
              w10 * bk[y0 * 3 + x0 + 1] + w11 * bk[(y0 + 1) * 3 + x0 + 1];
    rotw[e] = f2bf(v);
}

// ---- conv helpers: B-frag window load + one dy-phase of MFMAs ----
// frag(trow, ct, dx): sX row rr = wv*2 + trow, col cc = ct*16 + nlo + 1 + dx.
// pB = &sX[((wv*8 + quad)*66 + nlo + 1) * 8]; offsets are compile-time after unroll.
__device__ __forceinline__ void loadF(short8 (&F)[12], const unsigned short* pB, int trow) {
#pragma unroll
    for (int ct = 0; ct < 4; ++ct)
#pragma unroll
        for (int dxx = 0; dxx < 3; ++dxx)
            F[ct * 3 + dxx] = *(const short8*)(pB + trow * 2112 + ct * 128 + dxx * 8 - 8);
}

__device__ __forceinline__ void phase(floatx4 (&acc0)[8], floatx4 (&acc1)[8],
                                      const short8 (&F0)[12], const short8 (&F1)[12],
                                      const unsigned short* sW, int k9b, int nlo, int quad) {
#pragma unroll
    for (int dxx = 0; dxx < 3; ++dxx) {
        int k9 = k9b + dxx;
        short8 a0 = *(const short8*)&sW[((k9 * 32) + nlo) * 32 + quad * 8];
        short8 a1 = *(const short8*)&sW[((k9 * 32) + 16 + nlo) * 32 + quad * 8];
#pragma unroll
        for (int ct = 0; ct < 4; ++ct) {
            int fi = ct * 3 + dxx;
            acc0[ct]     = __builtin_amdgcn_mfma_f32_16x16x32_bf16(a0, F0[fi], acc0[ct], 0, 0, 0);
            acc1[ct]     = __builtin_amdgcn_mfma_f32_16x16x32_bf16(a1, F0[fi], acc1[ct], 0, 0, 0);
            acc0[4 + ct] = __builtin_amdgcn_mfma_f32_16x16x32_bf16(a0, F1[fi], acc0[4 + ct], 0, 0, 0);
            acc1[4 + ct] = __builtin_amdgcn_mfma_f32_16x16x32_bf16(a1, F1[fi], acc1[4 + ct], 0, 0, 0);
        }
    }
}

// ---------------- Kernel 4: MFMA implicit-GEMM grouped conv + SE gate ----------------
// grid: (128 bg, 8 strips of 8 rows). Block 256 = 4 waves.
// sX layout [r 0..9][q 0..3][c 0..65][8ci] bf16; sW layout [k9][co][ci] bf16.
// B-frags register-cached in two 12-frag rolling windows: frag rows are shared
// between (m=0,dy+1) and (m=1,dy) -> 48 distinct B ds_reads instead of 72.
// MFMA accumulation order per acc is k9 = 0..8 exactly as before (bit-identical).
__global__ __launch_bounds__(256, 2) void conv_mfma(const unsigned short* __restrict__ xT,
                                                    const unsigned short* __restrict__ rotw,
                                                    const float* __restrict__ modg,
                                                    float* __restrict__ out) {
    __shared__ __align__(16) unsigned short sW[9 * 32 * 32];      // 18432 B
    __shared__ __align__(16) unsigned short sX[10 * 4 * 66 * 8];  // 42240 B
    __shared__ float smod[32];
    int bg = blockIdx.x;
    int b = bg >> 3, g = bg & 7;
    int r0 = blockIdx.y * 8;
    int tid = threadIdx.x;
    int lane = tid & 63;
    int wv = tid >> 6;        // 0..3 -> rows wv*2, wv*2+1

    if (tid < 32) smod[tid] = modg[b * C_ + g * CG_ + tid];

    // ---- stage weights: 1152 chunks of 16B, async ----
#pragma unroll
    for (int i = 0; i < 5; ++i) {
        int idx = tid + i * 256;
        if (idx < 1152)  // i=4: waves 0,1 fully active, waves 2,3 fully off
            gld16(rotw + (size_t)bg * 9216 + idx * 8, &sW[idx * 8]);
    }

    // ---- stage x: 40 slabs (r,q); wave wv stages slab s = wv + i*4 ----
#pragma unroll
    for (int i = 0; i < 10; ++i) {
        int s = wv + i * 4;           // 0..39
        int r = s >> 2, q = s & 3;
        int grow = r0 - 1 + r;
        unsigned short* lp = &sX[((size_t)s * 66 + 1 + lane) * 8];
        if (grow >= 0 && grow < H_) {
            gld16(xT + ((((size_t)bg * 64 + grow) * 4 + q) * 64 + lane) * 8, lp);
        } else {
            *(short8*)lp = (short8){0, 0, 0, 0, 0, 0, 0, 0};
        }
    }
    // column halos (c=0 and c=65) for all 40 slabs
    if (tid < 80) {
        int s = tid >> 1, side = tid & 1;
        *(short8*)&sX[((size_t)s * 66 + side * 65) * 8] = (short8){0, 0, 0, 0, 0, 0, 0, 0};
    }
    __syncthreads();

    int nlo = lane & 15;      // px within N-tile / co within M-tile (A)
    int quad = lane >> 4;     // ci-octet selector

    floatx4 acc0[8], acc1[8];
#pragma unroll
    for (int nt = 0; nt < 8; ++nt) {
        acc0[nt] = (floatx4){0.f, 0.f, 0.f, 0.f};
        acc1[nt] = (floatx4){0.f, 0.f, 0.f, 0.f};
    }

    const unsigned short* pB = &sX[((size_t)(wv * 8 + quad) * 66 + nlo + 1) * 8];

    short8 Fa[12], Fb[12];
    loadF(Fa, pB, 0);                 // trow 0
    loadF(Fb, pB, 1);                 // trow 1
    phase(acc0, acc1, Fa, Fb, sW, 0, nlo, quad);   // dy=-1: m0<-trow0, m1<-trow1
    loadF(Fa, pB, 2);                 // trow 2
    phase(acc0, acc1, Fb, Fa, sW, 3, nlo, quad);   // dy= 0: m0<-trow1, m1<-trow2
    loadF(Fb, pB, 3);                 // trow 3
    phase(acc0, acc1, Fa, Fb, sW, 6, nlo, quad);   // dy=+1: m0<-trow2, m1<-trow3

    // ---- epilogue: D col = lane&15 (px), row = quad*4+reg (co) ----
    float gm[2][4];
#pragma unroll
    for (int mt = 0; mt < 2; ++mt)
#pragma unroll
        for (int reg = 0; reg < 4; ++reg) gm[mt][reg] = smod[mt * 16 + quad * 4 + reg];

#pragma unroll
    for (int nt = 0; nt < 8; ++nt) {
        int row = r0 + wv * 2 + (nt >> 2);
        int col = (nt & 3) * 16 + nlo;
#pragma unroll
        for (int reg = 0; reg < 4; ++reg) {
            int co0 = quad * 4 + reg;
            __builtin_nontemporal_store(acc0[nt][reg] * gm[0][reg],
                &out[((size_t)(b * C_ + g * CG_ + co0) * H_ + row) * W_ + col]);
            int co1 = 16 + quad * 4 + reg;
            __builtin_nontemporal_store(acc1[nt][reg] * gm[1][reg],
                &out[((size_t)(b * C_ + g * CG_ + co1) * H_ + row) * W_ + col]);
        }
    }
}

extern "C" void kernel_launch(void* const* d_in, const int* in_sizes, int n_in,
                              void* d_out, int out_size, void* d_ws, size_t ws_size,
                              hipStream_t stream) {
    const float* x      = (const float*)d_in[0];
    const float* basek  = (const float*)d_in[1];
    const float* ap_w1  = (const float*)d_in[2];
    const float* ap_b1  = (const float*)d_in[3];
    const float* ap_w2  = (const float*)d_in[4];
    const float* ap_b2  = (const float*)d_in[5];
    const float* mw1    = (const float*)d_in[6];
    const float* mb1    = (const float*)d_in[7];
    const float* mw2    = (const float*)d_in[8];
    const float* mb2    = (const float*)d_in[9];
    float* out = (float*)d_out;

    // Workspace (floats):
    //   rowsum  [0, 262144)          — 1 MB   [bg][h][ci]
    //   angles  [262144, 262272)
    //   modg    [262272, 266368)
    //   rotw    bf16 @ float-off 266368 (byte 1065472, 16B aligned), 2359296 B
    //   xT      bf16 @ float-off 856192 (byte 3424768, 16B aligned), 33554432 B
    float* wsf    = (float*)d_ws;
    float* rowsum = wsf;
    float* angles = wsf + 262144;
    float* modg   = wsf + 262272;
    unsigned short* rotw = (unsigned short*)(wsf + 266368);
    unsigned short* xT   = (unsigned short*)(wsf + 856192);

    xpose_pool<<<B_ * G_ * H_, 256, 0, stream>>>(x, xT, rowsum);
    mlp_kernel<<<B_, 256, 0, stream>>>(rowsum, ap_w1, ap_b1, ap_w2, ap_b2,
                                       mw1, mb1, mw2, mb2, angles, modg);
    rot_kernel<<<(B_ * G_ * CG_ * CG_ * 9) / 256, 256, 0, stream>>>(basek, angles, rotw);
    dim3 cgrid(B_ * G_, H_ / 8);
    conv_mfma<<<cgrid, 256, 0, stream>>>(xT, rotw, modg, out);
}

// Round 4
// 162.682 us; speedup vs baseline: 1.0436x; 1.0436x over previous
//
#include <hip/hip_runtime.h>
#include <math.h>

// Problem constants
#define B_ 16
#define C_ 256
#define H_ 64
#define W_ 64
#define G_ 8
#define CG_ 32
#define HID_ 64

typedef __attribute__((ext_vector_type(8))) short short8;
typedef __attribute__((ext_vector_type(4))) float floatx4;

__device__ inline unsigned short f2bf(float f) {
    union { float f; unsigned u; } v; v.f = f;
    unsigned r = v.u + 0x7fffu + ((v.u >> 16) & 1u);  // round-to-nearest-even
    return (unsigned short)(r >> 16);
}

// async global->LDS 16B copy (wave-uniform LDS base + lane*16 — all call sites
// keep lane-contiguous LDS destinations and wave-uniform branches)
__device__ __forceinline__ void gld16(const void* g, void* l) {
    __builtin_amdgcn_global_load_lds(
        (const __attribute__((address_space(1))) unsigned int*)g,
        (__attribute__((address_space(3))) unsigned int*)l, 16, 0, 0);
}

// ---- Kernel 1: transpose x -> bf16 xT[bg][h][q][w][8ci]  +  rowsum[bg][h][ci] ----
// block = (bg,h): 256 threads, wave q handles ci-octet q; lane w = column.
__global__ void xpose_pool(const float* __restrict__ x,
                           unsigned short* __restrict__ xT,
                           float* __restrict__ rowsum) {
    int bid = blockIdx.x;           // bg*64 + h
    int tid = threadIdx.x;
    int w = tid & 63, q = tid >> 6; // q = wave id (0..3)
    int h = bid & 63, bg = bid >> 6;

    const float* src = x + (((size_t)bg * 32 + q * 8) * 64 + h) * 64 + w;
    float v[8];
#pragma unroll
    for (int j = 0; j < 8; ++j) v[j] = src[(size_t)j * 4096];

    short8 sv;
#pragma unroll
    for (int j = 0; j < 8; ++j) sv[j] = (short)f2bf(v[j]);
    *(short8*)(xT + ((size_t)(bid * 4 + q) * 64 + w) * 8) = sv;

    // per-ci row sums: reduce each v[j] over the 64 w-lanes
#pragma unroll
    for (int j = 0; j < 8; ++j) {
#pragma unroll
        for (int off = 32; off > 0; off >>= 1) v[j] += __shfl_down(v[j], off, 64);
    }
    if (w == 0) {
        float* rs = rowsum + (size_t)bid * 32 + q * 8;
#pragma unroll
        for (int j = 0; j < 8; ++j) rs[j] = v[j];
    }
}

// ---------------- Kernel 2: MLPs -> angles[B,G], mod[B,C] ----------------
// rowsum block slice for b: 16384 floats (64 KB) contiguous. Stage in two 32 KB
// halves via global_load_lds (coalesced), reduce over h from LDS (2 lanes/bank = free).
__global__ void mlp_kernel(const float* __restrict__ rowsum,
                           const float* __restrict__ ap_w1, const float* __restrict__ ap_b1,
                           const float* __restrict__ ap_w2, const float* __restrict__ ap_b2,
                           const float* __restrict__ mw1, const float* __restrict__ mb1,
                           const float* __restrict__ mw2, const float* __restrict__ mb2,
                           float* __restrict__ angles, float* __restrict__ modg) {
    int b = blockIdx.x, tid = threadIdx.x;
    __shared__ __align__(16) float sL[8192];   // 32 KB staging
    __shared__ __align__(16) float sp[C_];
    __shared__ __align__(16) float ha[HID_], hm[HID_];

    const float* rs = rowsum + (size_t)b * 16384;
    float s = 0.f;
#pragma unroll
    for (int p = 0; p < 2; ++p) {
        // stage 8192 floats = 2048 16B-chunks: chunk = tid + i*256
#pragma unroll
        for (int i = 0; i < 8; ++i) {
            int chunk = tid + i * 256;
            gld16(rs + (size_t)p * 8192 + chunk * 4, &sL[chunk * 4]);
        }
        __syncthreads();   // compiler drains vmcnt before s_barrier
        // pass p holds g in [4p, 4p+4): threads 128p..128p+127 accumulate
        if ((tid >> 7) == p) {
            int gl = (tid >> 5) & 3, ci = tid & 31;
            const float* base = &sL[gl * 2048 + ci];
#pragma unroll
            for (int h = 0; h < 64; ++h) s += base[h * 32];
        }
        __syncthreads();
    }
    sp[tid] = s * (1.0f / 4096.0f);
    __syncthreads();

    if (tid < 64) {
        const float4* wr = (const float4*)(ap_w1 + tid * C_);
        const float4* p4 = (const float4*)sp;
        float s2 = ap_b1[tid];
#pragma unroll
        for (int i = 0; i < 64; ++i) {
            float4 wv = wr[i], pv = p4[i];
            s2 = fmaf(pv.x, wv.x, s2); s2 = fmaf(pv.y, wv.y, s2);
            s2 = fmaf(pv.z, wv.z, s2); s2 = fmaf(pv.w, wv.w, s2);
        }
        ha[tid] = fmaxf(s2, 0.f);
    } else if (tid < 128) {
        int t = tid - 64;
        const float4* wr = (const float4*)(mw1 + t * C_);
        const float4* p4 = (const float4*)sp;
        float s2 = mb1[t];
#pragma unroll
        for (int i = 0; i < 64; ++i) {
            float4 wv = wr[i], pv = p4[i];
            s2 = fmaf(pv.x, wv.x, s2); s2 = fmaf(pv.y, wv.y, s2);
            s2 = fmaf(pv.z, wv.z, s2); s2 = fmaf(pv.w, wv.w, s2);
        }
        hm[t] = fmaxf(s2, 0.f);
    }
    __syncthreads();

    if (tid < G_) {
        const float* wr = ap_w2 + tid * HID_;
        float s2 = ap_b2[tid];
        for (int i = 0; i < HID_; ++i) s2 = fmaf(ha[i], wr[i], s2);
        angles[b * G_ + tid] = tanhf(s2) * 0.78539816339744830962f;  // pi/4
    }
    {
        const float* wr = mw2 + tid * HID_;
        float s2 = mb2[tid];
        for (int i = 0; i < HID_; ++i) s2 = fmaf(hm[i], wr[i], s2);
        modg[b * C_ + tid] = 1.0f / (1.0f + expf(-s2));
    }
}

// ---------------- Kernel 3: bilinear rotation -> rotw bf16 [bg][k9][co][ci] ----------------
__global__ void rot_kernel(const float* __restrict__ base, const float* __restrict__ angles,
                           unsigned short* __restrict__ rotw) {
    int e = blockIdx.x * 256 + threadIdx.x;  // total B*G*9*32*32 = 1179648
    int ci = e & 31;
    int co = (e >> 5) & 31;
    int t = e >> 10;       // bg*9 + k
    int k = t % 9;
    int bg = t / 9;
    int b = bg >> 3, g = bg & 7;

    float ang = angles[b * G_ + g];
    float cc = __cosf(ang), ss = __sinf(ang);
    int i = k / 3, j = k % 3;
    float fx = (float)(j - 1), fy = (float)(i - 1);
    float xr = fx * cc + fy * ss + 1.0f;
    float yr = -fx * ss + fy * cc + 1.0f;
    float x0f = fminf(fmaxf(floorf(xr), 0.f), 1.f);
    float y0f = fminf(fmaxf(floorf(yr), 0.f), 1.f);
    float w00 = (x0f + 1.f - xr) * (y0f + 1.f - yr);
    float w01 = (x0f + 1.f - xr) * (yr - y0f);
    float w10 = (xr - x0f) * (y0f + 1.f - yr);
    float w11 = (xr - x0f) * (yr - y0f);
    int x0 = (int)x0f, y0 = (int)y0f;

    const float* bk = base + (((size_t)(g * CG_ + co) * CG_ + ci) * 9);
    float v = w00 * bk[y0 * 3 + x0] + w01 * bk[(y0 + 1) * 3 + x0] +
              w10 * bk[y0 * 3 + x0 + 1] + w11 * bk[(y0 + 1) * 3 + x0 + 1];
    rotw[e] = f2bf(v);
}

// ---------------- Kernel 4: MFMA implicit-GEMM grouped conv + SE gate ----------------
// grid: (128 bg, 8 strips of 8 rows). Block 256 = 4 waves.
// sX layout [r 0..9][q 0..3][c 0..65][8ci] bf16 — each (r,q) slab of 64 cells is
// wave-contiguous 1KB -> staged by ONE global_load_lds sweep from xT.
// sW layout [k9][co][ci] bf16 (18KB) — staged linearly via global_load_lds.
__global__ __launch_bounds__(256, 2) void conv_mfma(const unsigned short* __restrict__ xT,
                                                    const unsigned short* __restrict__ rotw,
                                                    const float* __restrict__ modg,
                                                    float* __restrict__ out) {
    __shared__ __align__(16) unsigned short sW[9 * 32 * 32];      // 18432 B
    __shared__ __align__(16) unsigned short sX[10 * 4 * 66 * 8];  // 42240 B
    __shared__ float smod[32];
    int bg = blockIdx.x;
    int b = bg >> 3, g = bg & 7;
    int r0 = blockIdx.y * 8;
    int tid = threadIdx.x;
    int lane = tid & 63;
    int wv = tid >> 6;        // 0..3 -> rows wv*2, wv*2+1

    // ---- stage weights: 1152 chunks of 16B, async ----
#pragma unroll
    for (int i = 0; i < 5; ++i) {
        int idx = tid + i * 256;
        if (idx < 1152)  // i=4: waves 0,1 fully active, waves 2,3 fully off
            gld16(rotw + (size_t)bg * 9216 + idx * 8, &sW[idx * 8]);
    }

    // ---- stage x: 40 slabs (r,q); wave wv stages slab s = wv + i*4 ----
#pragma unroll
    for (int i = 0; i < 10; ++i) {
        int s = wv + i * 4;           // 0..39
        int r = s >> 2, q = s & 3;
        int grow = r0 - 1 + r;
        unsigned short* lp = &sX[((size_t)s * 66 + 1 + lane) * 8];
        if (grow >= 0 && grow < H_) {
            gld16(xT + ((((size_t)bg * 64 + grow) * 4 + q) * 64 + lane) * 8, lp);
        } else {
            *(short8*)lp = (short8){0, 0, 0, 0, 0, 0, 0, 0};
        }
    }
    // column halos (c=0 and c=65) for all 40 slabs
    if (tid < 80) {
        int s = tid >> 1, side = tid & 1;
        *(short8*)&sX[((size_t)s * 66 + side * 65) * 8] = (short8){0, 0, 0, 0, 0, 0, 0, 0};
    }
    if (tid < 32) smod[tid] = modg[b * C_ + g * CG_ + tid];
    __syncthreads();

    int nlo = lane & 15;      // px within N-tile / co within M-tile (A)
    int quad = lane >> 4;     // ci-octet selector

    floatx4 acc0[8], acc1[8];
#pragma unroll
    for (int nt = 0; nt < 8; ++nt) {
        acc0[nt] = (floatx4){0.f, 0.f, 0.f, 0.f};
        acc1[nt] = (floatx4){0.f, 0.f, 0.f, 0.f};
    }

#pragma unroll
    for (int k9 = 0; k9 < 9; ++k9) {
        const int dy = k9 / 3 - 1, dx = k9 % 3 - 1;
        short8 a0 = *(const short8*)&sW[((k9 * 32) + nlo) * 32 + quad * 8];
        short8 a1 = *(const short8*)&sW[((k9 * 32) + 16 + nlo) * 32 + quad * 8];
#pragma unroll
        for (int nt = 0; nt < 8; ++nt) {
            int rr = wv * 2 + (nt >> 2) + 1 + dy;        // 0..9
            int cc = (nt & 3) * 16 + nlo + 1 + dx;       // 0..65
            short8 bf = *(const short8*)&sX[(((size_t)rr * 4 + quad) * 66 + cc) * 8];
            acc0[nt] = __builtin_amdgcn_mfma_f32_16x16x32_bf16(a0, bf, acc0[nt], 0, 0, 0);
            acc1[nt] = __builtin_amdgcn_mfma_f32_16x16x32_bf16(a1, bf, acc1[nt], 0, 0, 0);
        }
    }

    // ---- epilogue: D col = lane&15 (px), row = quad*4+reg (co) ----
    float gm[2][4];
#pragma unroll
    for (int mt = 0; mt < 2; ++mt)
#pragma unroll
        for (int reg = 0; reg < 4; ++reg) gm[mt][reg] = smod[mt * 16 + quad * 4 + reg];

#pragma unroll
    for (int nt = 0; nt < 8; ++nt) {
        int row = r0 + wv * 2 + (nt >> 2);
        int col = (nt & 3) * 16 + nlo;
#pragma unroll
        for (int reg = 0; reg < 4; ++reg) {
            int co0 = quad * 4 + reg;
            out[((size_t)(b * C_ + g * CG_ + co0) * H_ + row) * W_ + col] = acc0[nt][reg] * gm[0][reg];
            int co1 = 16 + quad * 4 + reg;
            out[((size_t)(b * C_ + g * CG_ + co1) * H_ + row) * W_ + col] = acc1[nt][reg] * gm[1][reg];
        }
    }
}

extern "C" void kernel_launch(void* const* d_in, const int* in_sizes, int n_in,
                              void* d_out, int out_size, void* d_ws, size_t ws_size,
                              hipStream_t stream) {
    const float* x      = (const float*)d_in[0];
    const float* basek  = (const float*)d_in[1];
    const float* ap_w1  = (const float*)d_in[2];
    const float* ap_b1  = (const float*)d_in[3];
    const float* ap_w2  = (const float*)d_in[4];
    const float* ap_b2  = (const float*)d_in[5];
    const float* mw1    = (const float*)d_in[6];
    const float* mb1    = (const float*)d_in[7];
    const float* mw2    = (const float*)d_in[8];
    const float* mb2    = (const float*)d_in[9];
    float* out = (float*)d_out;

    // Workspace (floats):
    //   rowsum  [0, 262144)          — 1 MB   [bg][h][ci]
    //   angles  [262144, 262272)
    //   modg    [262272, 266368)
    //   rotw    bf16 @ float-off 266368 (byte 1065472, 16B aligned), 2359296 B
    //   xT      bf16 @ float-off 856192 (byte 3424768, 16B aligned), 33554432 B
    float* wsf    = (float*)d_ws;
    float* rowsum = wsf;
    float* angles = wsf + 262144;
    float* modg   = wsf + 262272;
    unsigned short* rotw = (unsigned short*)(wsf + 266368);
    unsigned short* xT   = (unsigned short*)(wsf + 856192);

    xpose_pool<<<B_ * G_ * H_, 256, 0, stream>>>(x, xT, rowsum);
    mlp_kernel<<<B_, 256, 0, stream>>>(rowsum, ap_w1, ap_b1, ap_w2, ap_b2,
                                       mw1, mb1, mw2, mb2, angles, modg);
    rot_kernel<<<(B_ * G_ * CG_ * CG_ * 9) / 256, 256, 0, stream>>>(basek, angles, rotw);
    dim3 cgrid(B_ * G_, H_ / 8);
    conv_mfma<<<cgrid, 256, 0, stream>>>(xT, rotw, modg, out);
}